// Round 7
// baseline (258.043 us; speedup 1.0000x reference)
//
#include <hip/hip_runtime.h>
#include <hip/hip_bf16.h>

typedef __attribute__((ext_vector_type(8))) short short8;
typedef __attribute__((ext_vector_type(4))) float f32x4;
typedef __attribute__((ext_vector_type(4))) unsigned short us4;

#define NE  1024
#define SEQ 2048

__device__ __forceinline__ float bf2f(unsigned short u) {
    union { unsigned u; float f; } x; x.u = ((unsigned)u) << 16; return x.f;
}
__device__ __forceinline__ unsigned short f2bf(float f) {   // RNE
    union { float f; unsigned u; } x; x.f = f;
    unsigned r = x.u + 0x7FFFu + ((x.u >> 16) & 1u);
    return (unsigned short)(r >> 16);
}
__device__ __forceinline__ unsigned short f2bf_fast(float f) { // round-half-up
    union { float f; unsigned u; } x; x.f = f;
    return (unsigned short)((x.u + 0x8000u) >> 16);
}

// Runtime input-dtype detect (1 = bf16, 0 = f32). Validated rounds 3-6.
__global__ void detect_dtype(const unsigned short* __restrict__ s,
                             int* __restrict__ flag) {
    __shared__ int cnt;
    const int t = threadIdx.x;
    if (t == 0) cnt = 0;
    __syncthreads();
    unsigned short u = s[t];
    int e = (u >> 7) & 0xFF;
    int sane = (e == 0) || (e >= 100 && e <= 140);
    atomicAdd(&cnt, sane);
    __syncthreads();
    if (t == 0) flag[0] = (cnt >= 230) ? 1 : 0;
}

struct Ptrs7 { const void* s[7]; unsigned short* d[7]; };

// One-time f32->bf16 convert (or bf16 copy) of q,k,v (z<3) and weights (z>=3).
__global__ void convert7(Ptrs7 p, const int* __restrict__ flag, int zoff) {
    const int z = blockIdx.z + zoff;
    const int n = (z < 3) ? (4 << 20) : (1 << 20);
    const bool in_f32 = (flag[0] == 0);
    unsigned short* d = p.d[z];
    const int stride = gridDim.x * blockDim.x;
    for (int i8 = blockIdx.x * blockDim.x + threadIdx.x; i8 * 8 < n; i8 += stride) {
        size_t off = (size_t)i8 * 8;
        if (in_f32) {
            const float* sp = (const float*)p.s[z] + off;
            float4 a = *(const float4*)sp, b2 = *(const float4*)(sp + 4);
            short8 sv;
            sv[0] = (short)f2bf(a.x);  sv[1] = (short)f2bf(a.y);
            sv[2] = (short)f2bf(a.z);  sv[3] = (short)f2bf(a.w);
            sv[4] = (short)f2bf(b2.x); sv[5] = (short)f2bf(b2.y);
            sv[6] = (short)f2bf(b2.z); sv[7] = (short)f2bf(b2.w);
            *(short8*)(d + off) = sv;
        } else {
            *(short8*)(d + off) = *(const short8*)((const unsigned short*)p.s[z] + off);
        }
    }
}

// m97-structure GEMM: C[4096][1024] = A @ W^T (+bias). 128x128 tile, BK=32,
// 256 threads = 4 waves, wave = 64x64. VT: z==2 writes V transposed per head
// into vt[b][h][d][s] (b64 packed stores: r=0..3 are consecutive s).
template<int AWS, int WWS, int OUTF, int VT>
__global__ __launch_bounds__(256, 3)
void gemm_bt(const void* A0, const void* A1, const void* A2,
             const void* W0, const void* W1, const void* W2,
             const void* b0, const void* b1, const void* b2,
             void* C0, void* C1, void* C2,
             const int* __restrict__ flag)
{
    __shared__ __align__(16) unsigned short As[128 * 32];
    __shared__ __align__(16) unsigned short Bs[128 * 32];
    const int z = blockIdx.z;
    const void* Ap = (z == 0) ? A0 : (z == 1) ? A1 : A2;
    const void* Wp = (z == 0) ? W0 : (z == 1) ? W1 : W2;
    const void* bp = (z == 0) ? b0 : (z == 1) ? b1 : b2;
    void*       Cp = (z == 0) ? C0 : (z == 1) ? C1 : C2;
    const bool in_f32 = (flag[0] == 0);
    const int t = threadIdx.x;
    const int w = t >> 6, l = t & 63, q = l >> 4, n = l & 15;
    const int m0 = blockIdx.y * 128, n0 = blockIdx.x * 128;
    const int wm = (w >> 1) * 64, wn = (w & 1) * 64;
    const int srow = t >> 2, sk = (t & 3) * 8;

    f32x4 acc[4][4] = {};

    for (int k0 = 0; k0 < NE; k0 += 32) {
        if (AWS || !in_f32) {
            #pragma unroll
            for (int hh = 0; hh < 2; hh++) {
                const unsigned short* ga = (const unsigned short*)Ap +
                    (size_t)(m0 + srow + hh * 64) * NE + k0 + sk;
                __builtin_amdgcn_global_load_lds(
                    (const __attribute__((address_space(1))) void*)ga,
                    (__attribute__((address_space(3))) void*)&As[hh * 2048 + w * 512],
                    16, 0, 0);
            }
        } else {
            #pragma unroll
            for (int hh = 0; hh < 2; hh++) {
                const float* a = (const float*)Ap +
                                 (size_t)(m0 + srow + hh * 64) * NE + k0 + sk;
                float4 x0 = *(const float4*)a, x1 = *(const float4*)(a + 4);
                short8 sv;
                sv[0] = (short)f2bf(x0.x); sv[1] = (short)f2bf(x0.y);
                sv[2] = (short)f2bf(x0.z); sv[3] = (short)f2bf(x0.w);
                sv[4] = (short)f2bf(x1.x); sv[5] = (short)f2bf(x1.y);
                sv[6] = (short)f2bf(x1.z); sv[7] = (short)f2bf(x1.w);
                *(short8*)(&As[hh * 2048 + t * 8]) = sv;
            }
        }
        if (WWS || !in_f32) {
            #pragma unroll
            for (int hh = 0; hh < 2; hh++) {
                const unsigned short* ga = (const unsigned short*)Wp +
                    (size_t)(n0 + srow + hh * 64) * NE + k0 + sk;
                __builtin_amdgcn_global_load_lds(
                    (const __attribute__((address_space(1))) void*)ga,
                    (__attribute__((address_space(3))) void*)&Bs[hh * 2048 + w * 512],
                    16, 0, 0);
            }
        } else {
            #pragma unroll
            for (int hh = 0; hh < 2; hh++) {
                const float* a = (const float*)Wp +
                                 (size_t)(n0 + srow + hh * 64) * NE + k0 + sk;
                float4 x0 = *(const float4*)a, x1 = *(const float4*)(a + 4);
                short8 sv;
                sv[0] = (short)f2bf(x0.x); sv[1] = (short)f2bf(x0.y);
                sv[2] = (short)f2bf(x0.z); sv[3] = (short)f2bf(x0.w);
                sv[4] = (short)f2bf(x1.x); sv[5] = (short)f2bf(x1.y);
                sv[6] = (short)f2bf(x1.z); sv[7] = (short)f2bf(x1.w);
                *(short8*)(&Bs[hh * 2048 + t * 8]) = sv;
            }
        }
        __syncthreads();

        short8 af[4], bfv[4];
        #pragma unroll
        for (int mt = 0; mt < 4; mt++)
            af[mt] = *(const short8*)(&As[(wm + mt * 16 + n) * 32 + q * 8]);
        #pragma unroll
        for (int nt = 0; nt < 4; nt++)
            bfv[nt] = *(const short8*)(&Bs[(wn + nt * 16 + n) * 32 + q * 8]);
        #pragma unroll
        for (int mt = 0; mt < 4; mt++)
            #pragma unroll
            for (int nt = 0; nt < 4; nt++)
                acc[mt][nt] = __builtin_amdgcn_mfma_f32_16x16x32_bf16(
                    af[mt], bfv[nt], acc[mt][nt], 0, 0, 0);
        __syncthreads();
    }

    #pragma unroll
    for (int mt = 0; mt < 4; mt++)
        #pragma unroll
        for (int nt = 0; nt < 4; nt++) {
            int row0 = m0 + wm + mt * 16 + q * 4;
            int col  = n0 + wn + nt * 16 + n;
            float bia = 0.f;
            if (bp)
                bia = in_f32 ? ((const float*)bp)[col]
                             : bf2f(((const unsigned short*)bp)[col]);
            if (VT && z == 2) {
                // vt[b][h][d][s]; r=0..3 -> consecutive s -> one b64 store
                int bb = row0 >> 11, s0 = row0 & 2047;
                int hh2 = col >> 6, dd = col & 63;
                us4 pk4;
                #pragma unroll
                for (int r = 0; r < 4; r++)
                    pk4[r] = f2bf(acc[mt][nt][r] + bia);
                *(us4*)((unsigned short*)Cp +
                        ((size_t)((bb * 16 + hh2) * 64 + dd) << 11) + s0) = pk4;
            } else {
                #pragma unroll
                for (int r = 0; r < 4; r++) {
                    float v2 = acc[mt][nt][r] + bia;
                    size_t idx = (size_t)(row0 + r) * NE + col;
                    if (OUTF && in_f32) ((float*)Cp)[idx] = v2;
                    else                ((unsigned short*)Cp)[idx] = f2bf(v2);
                }
            }
        }
}

// Flash-style causal attention, flat per-q-block scheduling, fixed-bias softmax.
// Grid (32,16,2) = 1024 blocks, 256 thr = 4 waves, wave = 16 q-rows.
// K-tiles of 128 staged per barrier-pair; computed as two 64-key halves;
// fully-masked halves skipped (wave-uniform). qb = 31-bx: longest blocks first.
// V comes pre-transposed in vt[b][h][d][s] -> staging is a straight b128 copy.
// ctx may alias qh: block reads only the q-rows it later writes.
__global__ __launch_bounds__(256, 3)
void attn(const unsigned short* qh, const unsigned short* kh,
          const unsigned short* vt, unsigned short* ctx)
{
    __shared__ __align__(16) unsigned short Ks[128 * 72];   // [j_local][d], pad 72
    __shared__ __align__(16) unsigned short Vt[64 * 136];   // [d][j_local], pad 136
    __shared__ __align__(16) unsigned short Ps[4][16 * 72]; // per-wave P (64-key half)
    const int t = threadIdx.x, w = t >> 6, l = t & 63;
    const int q = l >> 4, n = l & 15;
    const int qb = 31 - blockIdx.x;
    const int h = blockIdx.y, b = blockIdx.z;
    const size_t base = (size_t)b * SEQ * NE + h * 64;
    const size_t vbase = (size_t)((b * 16 + h) * 64) << 11;   // vt[b][h][0][0]
    const int i0 = qb * 64 + w * 16;

    short8 qf[2];
    qf[0] = *(const short8*)(&qh[base + (size_t)(i0 + n) * NE + q * 8]);
    qf[1] = *(const short8*)(&qh[base + (size_t)(i0 + n) * NE + 32 + q * 8]);

    f32x4 o[4] = {};
    float ls[4] = {0.f, 0.f, 0.f, 0.f};

    const float K1 = 0.125f * 1.4426950408889634f;
    const float B2 = 24.0f * 1.4426950408889634f;

    // staging maps: 1024 b128 chunks each for K and V^T, 4 per thread
    const int jtmax = qb >> 1;
    short8 pk[4], pv[4];
    #pragma unroll
    for (int i = 0; i < 4; i++) {
        int c = t + i * 256;
        pk[i] = *(const short8*)(&kh[base + (size_t)(c >> 3) * NE + (c & 7) * 8]);
        pv[i] = *(const short8*)(&vt[vbase + ((size_t)(c >> 4) << 11) + (c & 15) * 8]);
    }

    unsigned short* PsW = &Ps[w][0];

    for (int jt = 0; jt <= jtmax; jt++) {
        // ---- drain prefetch regs into LDS ----
        #pragma unroll
        for (int i = 0; i < 4; i++) {
            int c = t + i * 256;
            *(short8*)(&Ks[(c >> 3) * 72 + (c & 7) * 8]) = pk[i];
            *(short8*)(&Vt[(c >> 4) * 136 + (c & 15) * 8]) = pv[i];
        }
        __syncthreads();

        // ---- issue next tile's global loads (overlap with compute) ----
        if (jt < jtmax) {
            const int jn = (jt + 1) * 128;
            #pragma unroll
            for (int i = 0; i < 4; i++) {
                int c = t + i * 256;
                pk[i] = *(const short8*)(&kh[base + (size_t)(jn + (c >> 3)) * NE + (c & 7) * 8]);
                pv[i] = *(const short8*)(&vt[vbase + ((size_t)(c >> 4) << 11) + jn + (c & 15) * 8]);
            }
        }

        #pragma unroll
        for (int khalf = 0; khalf < 2; khalf++) {
            const int kstart = jt * 128 + khalf * 64;
            if (kstart > qb * 64) break;              // fully-masked half (wave-uniform)
            const bool diag = (kstart == qb * 64);
            const int kloc = khalf * 64;

            f32x4 sa[4] = {};
            #pragma unroll
            for (int ks = 0; ks < 2; ks++)
                #pragma unroll
                for (int nt = 0; nt < 4; nt++) {
                    short8 kf = *(const short8*)(&Ks[(kloc + nt * 16 + n) * 72 + ks * 32 + q * 8]);
                    sa[nt] = __builtin_amdgcn_mfma_f32_16x16x32_bf16(qf[ks], kf, sa[nt], 0, 0, 0);
                }

            #pragma unroll
            for (int nt = 0; nt < 4; nt++)
                #pragma unroll
                for (int r = 0; r < 4; r++) {
                    float e = fmaf(sa[nt][r], K1, -B2);
                    if (diag) {
                        int j = kstart + nt * 16 + n;
                        int i = i0 + q * 4 + r;
                        bool ok = (j < i) || (i == 0 && j == 0);
                        e = ok ? e : -256.0f;          // exp2(-256) == 0 exactly
                    }
                    float p = __builtin_amdgcn_exp2f(e);
                    ls[r] += p;
                    PsW[(q * 4 + r) * 72 + nt * 16 + n] = f2bf_fast(p);
                }
            asm volatile("s_waitcnt lgkmcnt(0)" ::: "memory"); // Ps write->read (wave-private)

            #pragma unroll
            for (int ks = 0; ks < 2; ks++) {
                short8 pf = *(const short8*)(&PsW[n * 72 + ks * 32 + q * 8]);
                #pragma unroll
                for (int dt = 0; dt < 4; dt++) {
                    short8 vf = *(const short8*)(&Vt[(dt * 16 + n) * 136 + kloc + ks * 32 + q * 8]);
                    o[dt] = __builtin_amdgcn_mfma_f32_16x16x32_bf16(pf, vf, o[dt], 0, 0, 0);
                }
            }
            asm volatile("" ::: "memory");  // keep next half's Ps writes below these reads
        }
        __syncthreads();   // protect Ks/Vt for next drain
    }

    #pragma unroll
    for (int r = 0; r < 4; r++)
        #pragma unroll
        for (int xm = 1; xm <= 8; xm <<= 1)
            ls[r] += __shfl_xor(ls[r], xm, 64);

    #pragma unroll
    for (int r = 0; r < 4; r++) {
        float inv = 1.0f / ls[r];
        #pragma unroll
        for (int dt = 0; dt < 4; dt++)
            ctx[base + (size_t)(i0 + q * 4 + r) * NE + dt * 16 + n] =
                f2bf(o[dt][r] * inv);
    }
}

extern "C" void kernel_launch(void* const* d_in, const int* in_sizes, int n_in,
                              void* d_out, int out_size, void* d_ws, size_t ws_size,
                              hipStream_t stream) {
    const void* q  = d_in[0];
    const void* k  = d_in[1];
    const void* v  = d_in[2];
    const void* Wq = d_in[3];
    const void* Wk = d_in[4];
    const void* Wv = d_in[5];
    const void* bv = d_in[6];
    const void* Wo = d_in[7];
    const void* bo = d_in[8];

    const size_t MB = 1024 * 1024;
    const size_t M4 = 4 * MB;   // 4M shorts = 8 MB
    unsigned short* ws = (unsigned short*)d_ws;
    unsigned short* qh  = ws;               // [2,2048,1024] bf16
    unsigned short* kh  = ws + 1 * M4;      // [2,2048,1024] bf16
    unsigned short* vt  = ws + 2 * M4;      // [2,16,64,2048] bf16 (V transposed)
    unsigned short* ctx = qh;               // safe alias (see attn)

    int tier = (ws_size >= 56 * MB + 64) ? 2 : (ws_size >= 32 * MB + 64) ? 1 : 0;

    unsigned short *qc, *kc, *vc, *Wqc, *Wkc, *Wvc, *Woc;
    int* flag;
    if (tier == 2) {
        qc = ws + 3 * M4; kc = ws + 4 * M4; vc = ws + 5 * M4;
        Wqc = ws + 6 * M4;           Wkc = Wqc + 1 * MB;
        Wvc = Wqc + 2 * MB;          Woc = Wqc + 3 * MB;
        flag = (int*)((char*)d_ws + 56 * MB);
    } else if (tier == 1) {
        qc = kc = vc = nullptr;
        Wqc = ws + 3 * M4;           Wkc = Wqc + 1 * MB;
        Wvc = Wqc + 2 * MB;          Woc = Wqc + 3 * MB;
        flag = (int*)((char*)d_ws + 32 * MB);
    } else {
        qc = kc = vc = nullptr; Wqc = Wkc = Wvc = Woc = nullptr;
        flag = (int*)((char*)d_ws + 24 * MB);
    }

    detect_dtype<<<1, 256, 0, stream>>>((const unsigned short*)q, flag);

    if (tier > 0) {
        Ptrs7 p;
        p.s[0] = q;  p.s[1] = k;  p.s[2] = v;
        p.s[3] = Wq; p.s[4] = Wk; p.s[5] = Wv; p.s[6] = Wo;
        p.d[0] = qc; p.d[1] = kc; p.d[2] = vc;
        p.d[3] = Wqc; p.d[4] = Wkc; p.d[5] = Wvc; p.d[6] = Woc;
        if (tier == 2)
            convert7<<<dim3(512, 1, 7), 256, 0, stream>>>(p, flag, 0);
        else
            convert7<<<dim3(512, 1, 4), 256, 0, stream>>>(p, flag, 3);
    }

    if (tier == 2)
        gemm_bt<1, 1, 0, 1><<<dim3(8, 32, 3), 256, 0, stream>>>(
            qc, kc, vc, Wqc, Wkc, Wvc, nullptr, nullptr, bv, qh, kh, vt, flag);
    else if (tier == 1)
        gemm_bt<0, 1, 0, 1><<<dim3(8, 32, 3), 256, 0, stream>>>(
            q, k, v, Wqc, Wkc, Wvc, nullptr, nullptr, bv, qh, kh, vt, flag);
    else
        gemm_bt<0, 0, 0, 1><<<dim3(8, 32, 3), 256, 0, stream>>>(
            q, k, v, Wq, Wk, Wv, nullptr, nullptr, bv, qh, kh, vt, flag);

    attn<<<dim3(32, 16, 2), 256, 0, stream>>>(qh, kh, vt, ctx);

    if (tier > 0)
        gemm_bt<1, 1, 1, 0><<<dim3(8, 32, 1), 256, 0, stream>>>(
            ctx, ctx, ctx, Woc, Woc, Woc, bo, bo, bo, d_out, d_out, d_out, flag);
    else
        gemm_bt<1, 0, 1, 0><<<dim3(8, 32, 1), 256, 0, stream>>>(
            ctx, ctx, ctx, Wo, Wo, Wo, bo, bo, bo, d_out, d_out, d_out, flag);
}

// Round 8
// 229.739 us; speedup vs baseline: 1.1232x; 1.1232x over previous
//
#include <hip/hip_runtime.h>
#include <hip/hip_bf16.h>

typedef __attribute__((ext_vector_type(8))) short short8;
typedef __attribute__((ext_vector_type(4))) float f32x4;
typedef __attribute__((ext_vector_type(4))) unsigned short us4;

#define NE  1024
#define SEQ 2048

__device__ __forceinline__ float bf2f(unsigned short u) {
    union { unsigned u; float f; } x; x.u = ((unsigned)u) << 16; return x.f;
}
__device__ __forceinline__ unsigned short f2bf(float f) {   // RNE
    union { float f; unsigned u; } x; x.f = f;
    unsigned r = x.u + 0x7FFFu + ((x.u >> 16) & 1u);
    return (unsigned short)(r >> 16);
}
__device__ __forceinline__ unsigned short f2bf_fast(float f) { // round-half-up
    union { float f; unsigned u; } x; x.f = f;
    return (unsigned short)((x.u + 0x8000u) >> 16);
}

// Runtime input-dtype detect (1 = bf16, 0 = f32). Validated rounds 3-7.
__global__ void detect_dtype(const unsigned short* __restrict__ s,
                             int* __restrict__ flag) {
    __shared__ int cnt;
    const int t = threadIdx.x;
    if (t == 0) cnt = 0;
    __syncthreads();
    unsigned short u = s[t];
    int e = (u >> 7) & 0xFF;
    int sane = (e == 0) || (e >= 100 && e <= 140);
    atomicAdd(&cnt, sane);
    __syncthreads();
    if (t == 0) flag[0] = (cnt >= 230) ? 1 : 0;
}

struct Ptrs7 { const void* s[7]; unsigned short* d[7]; };

// One-time f32->bf16 convert (or bf16 copy) of q,k,v (z<3) and weights (z>=3).
__global__ void convert7(Ptrs7 p, const int* __restrict__ flag, int zoff) {
    const int z = blockIdx.z + zoff;
    const int n = (z < 3) ? (4 << 20) : (1 << 20);
    const bool in_f32 = (flag[0] == 0);
    unsigned short* d = p.d[z];
    const int stride = gridDim.x * blockDim.x;
    for (int i8 = blockIdx.x * blockDim.x + threadIdx.x; i8 * 8 < n; i8 += stride) {
        size_t off = (size_t)i8 * 8;
        if (in_f32) {
            const float* sp = (const float*)p.s[z] + off;
            float4 a = *(const float4*)sp, b2 = *(const float4*)(sp + 4);
            short8 sv;
            sv[0] = (short)f2bf(a.x);  sv[1] = (short)f2bf(a.y);
            sv[2] = (short)f2bf(a.z);  sv[3] = (short)f2bf(a.w);
            sv[4] = (short)f2bf(b2.x); sv[5] = (short)f2bf(b2.y);
            sv[6] = (short)f2bf(b2.z); sv[7] = (short)f2bf(b2.w);
            *(short8*)(d + off) = sv;
        } else {
            *(short8*)(d + off) = *(const short8*)((const unsigned short*)p.s[z] + off);
        }
    }
}

// m97-structure GEMM: C[4096][1024] = A @ W^T (+bias). 128x128 tile, BK=32,
// 256 threads = 4 waves, wave = 64x64. VT: z==2 writes V transposed per head
// into vt[b][h][d][s] (b64 packed stores: r=0..3 are consecutive s). Validated R7.
template<int AWS, int WWS, int OUTF, int VT>
__global__ __launch_bounds__(256, 3)
void gemm_bt(const void* A0, const void* A1, const void* A2,
             const void* W0, const void* W1, const void* W2,
             const void* b0, const void* b1, const void* b2,
             void* C0, void* C1, void* C2,
             const int* __restrict__ flag)
{
    __shared__ __align__(16) unsigned short As[128 * 32];
    __shared__ __align__(16) unsigned short Bs[128 * 32];
    const int z = blockIdx.z;
    const void* Ap = (z == 0) ? A0 : (z == 1) ? A1 : A2;
    const void* Wp = (z == 0) ? W0 : (z == 1) ? W1 : W2;
    const void* bp = (z == 0) ? b0 : (z == 1) ? b1 : b2;
    void*       Cp = (z == 0) ? C0 : (z == 1) ? C1 : C2;
    const bool in_f32 = (flag[0] == 0);
    const int t = threadIdx.x;
    const int w = t >> 6, l = t & 63, q = l >> 4, n = l & 15;
    const int m0 = blockIdx.y * 128, n0 = blockIdx.x * 128;
    const int wm = (w >> 1) * 64, wn = (w & 1) * 64;
    const int srow = t >> 2, sk = (t & 3) * 8;

    f32x4 acc[4][4] = {};

    for (int k0 = 0; k0 < NE; k0 += 32) {
        if (AWS || !in_f32) {
            #pragma unroll
            for (int hh = 0; hh < 2; hh++) {
                const unsigned short* ga = (const unsigned short*)Ap +
                    (size_t)(m0 + srow + hh * 64) * NE + k0 + sk;
                __builtin_amdgcn_global_load_lds(
                    (const __attribute__((address_space(1))) void*)ga,
                    (__attribute__((address_space(3))) void*)&As[hh * 2048 + w * 512],
                    16, 0, 0);
            }
        } else {
            #pragma unroll
            for (int hh = 0; hh < 2; hh++) {
                const float* a = (const float*)Ap +
                                 (size_t)(m0 + srow + hh * 64) * NE + k0 + sk;
                float4 x0 = *(const float4*)a, x1 = *(const float4*)(a + 4);
                short8 sv;
                sv[0] = (short)f2bf(x0.x); sv[1] = (short)f2bf(x0.y);
                sv[2] = (short)f2bf(x0.z); sv[3] = (short)f2bf(x0.w);
                sv[4] = (short)f2bf(x1.x); sv[5] = (short)f2bf(x1.y);
                sv[6] = (short)f2bf(x1.z); sv[7] = (short)f2bf(x1.w);
                *(short8*)(&As[hh * 2048 + t * 8]) = sv;
            }
        }
        if (WWS || !in_f32) {
            #pragma unroll
            for (int hh = 0; hh < 2; hh++) {
                const unsigned short* ga = (const unsigned short*)Wp +
                    (size_t)(n0 + srow + hh * 64) * NE + k0 + sk;
                __builtin_amdgcn_global_load_lds(
                    (const __attribute__((address_space(1))) void*)ga,
                    (__attribute__((address_space(3))) void*)&Bs[hh * 2048 + w * 512],
                    16, 0, 0);
            }
        } else {
            #pragma unroll
            for (int hh = 0; hh < 2; hh++) {
                const float* a = (const float*)Wp +
                                 (size_t)(n0 + srow + hh * 64) * NE + k0 + sk;
                float4 x0 = *(const float4*)a, x1 = *(const float4*)(a + 4);
                short8 sv;
                sv[0] = (short)f2bf(x0.x); sv[1] = (short)f2bf(x0.y);
                sv[2] = (short)f2bf(x0.z); sv[3] = (short)f2bf(x0.w);
                sv[4] = (short)f2bf(x1.x); sv[5] = (short)f2bf(x1.y);
                sv[6] = (short)f2bf(x1.z); sv[7] = (short)f2bf(x1.w);
                *(short8*)(&Bs[hh * 2048 + t * 8]) = sv;
            }
        }
        __syncthreads();

        short8 af[4], bfv[4];
        #pragma unroll
        for (int mt = 0; mt < 4; mt++)
            af[mt] = *(const short8*)(&As[(wm + mt * 16 + n) * 32 + q * 8]);
        #pragma unroll
        for (int nt = 0; nt < 4; nt++)
            bfv[nt] = *(const short8*)(&Bs[(wn + nt * 16 + n) * 32 + q * 8]);
        #pragma unroll
        for (int mt = 0; mt < 4; mt++)
            #pragma unroll
            for (int nt = 0; nt < 4; nt++)
                acc[mt][nt] = __builtin_amdgcn_mfma_f32_16x16x32_bf16(
                    af[mt], bfv[nt], acc[mt][nt], 0, 0, 0);
        __syncthreads();
    }

    #pragma unroll
    for (int mt = 0; mt < 4; mt++)
        #pragma unroll
        for (int nt = 0; nt < 4; nt++) {
            int row0 = m0 + wm + mt * 16 + q * 4;
            int col  = n0 + wn + nt * 16 + n;
            float bia = 0.f;
            if (bp)
                bia = in_f32 ? ((const float*)bp)[col]
                             : bf2f(((const unsigned short*)bp)[col]);
            if (VT && z == 2) {
                // vt[b][h][d][s]; r=0..3 -> consecutive s -> one b64 store
                int bb = row0 >> 11, s0 = row0 & 2047;
                int hh2 = col >> 6, dd = col & 63;
                us4 pk4;
                #pragma unroll
                for (int r = 0; r < 4; r++)
                    pk4[r] = f2bf(acc[mt][nt][r] + bia);
                *(us4*)((unsigned short*)Cp +
                        ((size_t)((bb * 16 + hh2) * 64 + dd) << 11) + s0) = pk4;
            } else {
                #pragma unroll
                for (int r = 0; r < 4; r++) {
                    float v2 = acc[mt][nt][r] + bia;
                    size_t idx = (size_t)(row0 + r) * NE + col;
                    if (OUTF && in_f32) ((float*)Cp)[idx] = v2;
                    else                ((unsigned short*)Cp)[idx] = f2bf(v2);
                }
            }
        }
}

// Flash-style causal attention — R6 structure (paired q-blocks, uniform block
// work) + pre-transposed V (straight b128 staging copy, no pack VALU).
// 512 threads = 8 waves; waves 0-3 -> q-block A (31-pair), waves 4-7 -> B (pair).
// One K/V staging shared by all 8 waves; B-waves sleep at barrier once jt>qbB.
// Grid (16,16,2) = 512 blocks = 2 blocks/CU = 16 waves/CU resident.
// ctx may alias qh: block reads only the q-rows it later writes.
__global__ __launch_bounds__(512, 4)
void attn(const unsigned short* qh, const unsigned short* kh,
          const unsigned short* vt, unsigned short* ctx)
{
    __shared__ __align__(16) unsigned short Ks[64 * 72];    // [j][d], pad 72
    __shared__ __align__(16) unsigned short Vt[64 * 72];    // [d][j], pad 72
    __shared__ __align__(16) unsigned short Ps[8][16 * 72]; // per-wave P
    const int t = threadIdx.x, w = t >> 6, l = t & 63;
    const int q = l >> 4, n = l & 15;
    const int half = w >> 2, sub = w & 3;
    const int pair = blockIdx.x;
    const int qbB = pair, qbA = 31 - pair;
    const int qb = half ? qbB : qbA;
    const int h = blockIdx.y, b = blockIdx.z;
    const size_t base = (size_t)b * SEQ * NE + h * 64;
    const size_t vbase = (size_t)((b * 16 + h) * 64) << 11;   // vt[b][h][0][0]
    const int i0 = qb * 64 + sub * 16;

    short8 qf[2];
    qf[0] = *(const short8*)(&qh[base + (size_t)(i0 + n) * NE + q * 8]);
    qf[1] = *(const short8*)(&qh[base + (size_t)(i0 + n) * NE + 32 + q * 8]);

    f32x4 o[4] = {};
    float ls[4] = {0.f, 0.f, 0.f, 0.f};

    const float K1 = 0.125f * 1.4426950408889634f;
    const float B2 = 24.0f * 1.4426950408889634f;

    // staging maps: 512 b128 chunks each for K and V^T, 1 per thread
    const int kr = t >> 3, kc = (t & 7) * 8;           // K: [row][8col]
    const int vd = t >> 3, vj = (t & 7) * 8;           // V^T: [d][8j]

    short8 pk, pv;
    pk = *(const short8*)(&kh[base + (size_t)kr * NE + kc]);
    pv = *(const short8*)(&vt[vbase + ((size_t)vd << 11) + vj]);

    unsigned short* PsW = &Ps[w][0];

    for (int jt = 0; jt <= qbA; jt++) {
        // ---- drain prefetch regs into LDS (straight b128 copies) ----
        *(short8*)(&Ks[kr * 72 + kc]) = pk;
        *(short8*)(&Vt[vd * 72 + vj]) = pv;
        __syncthreads();

        // ---- issue next tile's global loads (overlap with compute) ----
        if (jt < qbA) {
            const int jn = (jt + 1) * 64;
            pk = *(const short8*)(&kh[base + (size_t)(jn + kr) * NE + kc]);
            pv = *(const short8*)(&vt[vbase + ((size_t)vd << 11) + jn + vj]);
        }

        if (jt <= qb) {     // wave-uniform; B-waves skip once jt > qbB
            f32x4 sa[4] = {};
            #pragma unroll
            for (int ks = 0; ks < 2; ks++)
                #pragma unroll
                for (int nt = 0; nt < 4; nt++) {
                    short8 kf = *(const short8*)(&Ks[(nt * 16 + n) * 72 + ks * 32 + q * 8]);
                    sa[nt] = __builtin_amdgcn_mfma_f32_16x16x32_bf16(qf[ks], kf, sa[nt], 0, 0, 0);
                }

            const bool diag = (jt == qb);
            #pragma unroll
            for (int nt = 0; nt < 4; nt++)
                #pragma unroll
                for (int r = 0; r < 4; r++) {
                    float e = fmaf(sa[nt][r], K1, -B2);
                    if (diag) {
                        int j = jt * 64 + nt * 16 + n;
                        int i = i0 + q * 4 + r;
                        bool ok = (j < i) || (i == 0 && j == 0);
                        e = ok ? e : -256.0f;      // exp2(-256) == 0 exactly
                    }
                    float p = __builtin_amdgcn_exp2f(e);
                    ls[r] += p;
                    PsW[(q * 4 + r) * 72 + nt * 16 + n] = f2bf_fast(p);
                }
            asm volatile("s_waitcnt lgkmcnt(0)" ::: "memory"); // Ps write->read (wave-private)

            #pragma unroll
            for (int ks = 0; ks < 2; ks++) {
                short8 pf = *(const short8*)(&PsW[n * 72 + ks * 32 + q * 8]);
                #pragma unroll
                for (int dt = 0; dt < 4; dt++) {
                    short8 vf = *(const short8*)(&Vt[(dt * 16 + n) * 72 + ks * 32 + q * 8]);
                    o[dt] = __builtin_amdgcn_mfma_f32_16x16x32_bf16(pf, vf, o[dt], 0, 0, 0);
                }
            }
        }
        __syncthreads();   // protect Ks/Vt for next drain
    }

    #pragma unroll
    for (int r = 0; r < 4; r++)
        #pragma unroll
        for (int xm = 1; xm <= 8; xm <<= 1)
            ls[r] += __shfl_xor(ls[r], xm, 64);

    #pragma unroll
    for (int r = 0; r < 4; r++) {
        float inv = 1.0f / ls[r];
        #pragma unroll
        for (int dt = 0; dt < 4; dt++)
            ctx[base + (size_t)(i0 + q * 4 + r) * NE + dt * 16 + n] =
                f2bf(o[dt][r] * inv);
    }
}

extern "C" void kernel_launch(void* const* d_in, const int* in_sizes, int n_in,
                              void* d_out, int out_size, void* d_ws, size_t ws_size,
                              hipStream_t stream) {
    const void* q  = d_in[0];
    const void* k  = d_in[1];
    const void* v  = d_in[2];
    const void* Wq = d_in[3];
    const void* Wk = d_in[4];
    const void* Wv = d_in[5];
    const void* bv = d_in[6];
    const void* Wo = d_in[7];
    const void* bo = d_in[8];

    const size_t MB = 1024 * 1024;
    const size_t M4 = 4 * MB;   // 4M shorts = 8 MB
    unsigned short* ws = (unsigned short*)d_ws;
    unsigned short* qh  = ws;               // [2,2048,1024] bf16
    unsigned short* kh  = ws + 1 * M4;      // [2,2048,1024] bf16
    unsigned short* vt  = ws + 2 * M4;      // [2,16,64,2048] bf16 (V transposed)
    unsigned short* ctx = qh;               // safe alias (see attn)

    int tier = (ws_size >= 56 * MB + 64) ? 2 : (ws_size >= 32 * MB + 64) ? 1 : 0;

    unsigned short *qc, *kc, *vc, *Wqc, *Wkc, *Wvc, *Woc;
    int* flag;
    if (tier == 2) {
        qc = ws + 3 * M4; kc = ws + 4 * M4; vc = ws + 5 * M4;
        Wqc = ws + 6 * M4;           Wkc = Wqc + 1 * MB;
        Wvc = Wqc + 2 * MB;          Woc = Wqc + 3 * MB;
        flag = (int*)((char*)d_ws + 56 * MB);
    } else if (tier == 1) {
        qc = kc = vc = nullptr;
        Wqc = ws + 3 * M4;           Wkc = Wqc + 1 * MB;
        Wvc = Wqc + 2 * MB;          Woc = Wqc + 3 * MB;
        flag = (int*)((char*)d_ws + 32 * MB);
    } else {
        qc = kc = vc = nullptr; Wqc = Wkc = Wvc = Woc = nullptr;
        flag = (int*)((char*)d_ws + 24 * MB);
    }

    detect_dtype<<<1, 256, 0, stream>>>((const unsigned short*)q, flag);

    if (tier > 0) {
        Ptrs7 p;
        p.s[0] = q;  p.s[1] = k;  p.s[2] = v;
        p.s[3] = Wq; p.s[4] = Wk; p.s[5] = Wv; p.s[6] = Wo;
        p.d[0] = qc; p.d[1] = kc; p.d[2] = vc;
        p.d[3] = Wqc; p.d[4] = Wkc; p.d[5] = Wvc; p.d[6] = Woc;
        if (tier == 2)
            convert7<<<dim3(512, 1, 7), 256, 0, stream>>>(p, flag, 0);
        else
            convert7<<<dim3(512, 1, 4), 256, 0, stream>>>(p, flag, 3);
    }

    if (tier == 2)
        gemm_bt<1, 1, 0, 1><<<dim3(8, 32, 3), 256, 0, stream>>>(
            qc, kc, vc, Wqc, Wkc, Wvc, nullptr, nullptr, bv, qh, kh, vt, flag);
    else if (tier == 1)
        gemm_bt<0, 1, 0, 1><<<dim3(8, 32, 3), 256, 0, stream>>>(
            q, k, v, Wqc, Wkc, Wvc, nullptr, nullptr, bv, qh, kh, vt, flag);
    else
        gemm_bt<0, 0, 0, 1><<<dim3(8, 32, 3), 256, 0, stream>>>(
            q, k, v, Wq, Wk, Wv, nullptr, nullptr, bv, qh, kh, vt, flag);

    attn<<<dim3(16, 16, 2), 512, 0, stream>>>(qh, kh, vt, ctx);

    if (tier > 0)
        gemm_bt<1, 1, 1, 0><<<dim3(8, 32, 1), 256, 0, stream>>>(
            ctx, ctx, ctx, Woc, Woc, Woc, bo, bo, bo, d_out, d_out, d_out, flag);
    else
        gemm_bt<1, 0, 1, 0><<<dim3(8, 32, 1), 256, 0, stream>>>(
            ctx, ctx, ctx, Wo, Wo, Wo, bo, bo, bo, d_out, d_out, d_out, flag);
}